// Round 6
// baseline (585.394 us; speedup 1.0000x reference)
//
#include <hip/hip_runtime.h>

#define H   128
#define P   32             // points per block
#define NT  384            // 6 waves: wave w owns state plane w

typedef _Float16 v8h __attribute__((ext_vector_type(8)));
typedef __fp16   h2  __attribute__((ext_vector_type(2)));   // cvt_pkrtz return type
typedef float    v4f __attribute__((ext_vector_type(4)));

union PK4 { h2 h[4]; uint4 u; };       // 8 f16 = 16 B
union PK2 { h2 h[2]; uint2 u; };       // 4 f16 = 8 B

// State plane layout: [pl][p][k], 128 f16 per row, XOR-octet swizzle so both
// row-wise b128 (k-octets at fixed p) and column-wise b64/b128 (p varying)
// accesses are 2-way-bank-aliased (free, m136). Returns f16 index of octet o.
__device__ __forceinline__ int soct(int pl, int p, int o) {
    return ((pl * P + p) * 16 + (o ^ (p & 15))) << 3;
}

// Coalesced tiled transpose+cvt: Wt[layer][j][k] = f16(W[k][j])
__global__ void wt_convert(const float* __restrict__ W1,
                           const float* __restrict__ W2,
                           _Float16* __restrict__ ws) {
    __shared__ float tile[32][33];
    const int b  = blockIdx.x;          // 0..31
    const int l  = b >> 4;
    const int t  = b & 15;
    const int kt = t >> 2, jt = t & 3;
    const float* __restrict__ W = l ? W2 : W1;
    const int tr = threadIdx.x >> 5;    // 0..7
    const int tc = threadIdx.x & 31;
    #pragma unroll
    for (int s = 0; s < 4; ++s)
        tile[tr + s * 8][tc] = W[(kt * 32 + tr + s * 8) * H + jt * 32 + tc];
    __syncthreads();
    #pragma unroll
    for (int s = 0; s < 4; ++s)
        ws[l * H * H + (jt * 32 + tr + s * 8) * H + kt * 32 + tc] =
            (_Float16)tile[tc][tr + s * 8];
}

__device__ __forceinline__ void tanh_d2(float z, float& a, float& g1, float& g2) {
    const float e = __expf(2.f * z);
    a  = 1.f - 2.f / (e + 1.f);
    g1 = 1.f - a * a;
    g2 = -2.f * a * g1;
}

// Second-order forward-mode Hessian via f16 MFMA, zT orientation.
//   GEMM: zT[j][p] = sum_k Wt[j][k] * S[pl][p][k]
//   A = Wt (m=j, from GLOBAL - L1-resident 32KB), B = state (n=p, from LDS)
//   C layout: row j = quad*4+r (4 consecutive j per lane -> b64 writeback),
//             col p = lane&15.
__global__ __launch_bounds__(NT, 3)
void pinn_hess_mfma(const float* __restrict__ X,
                    const float* __restrict__ W0, const float* __restrict__ b0,
                    const _Float16* __restrict__ Wt,
                    const float* __restrict__ b1, const float* __restrict__ b2,
                    const float* __restrict__ W3,
                    float* __restrict__ out, int N)
{
    __shared__ _Float16 sS[6 * P * H];   // 49152 B, swizzled planes

    const int tid   = threadIdx.x;
    const int wave  = tid >> 6;          // 0..5 == plane id
    const int lane  = tid & 63;
    const int quad  = lane >> 4;
    const int l15   = lane & 15;
    const int pbase = blockIdx.x * P;

    // ---------------- layer 0 (input dim 2, analytic) ----------------
    for (int i = tid; i < P * 16; i += NT) {     // task = (p, j-octet)
        const int p = i >> 4, o = i & 15;
        const float x = X[2 * (pbase + p)];
        const float y = X[2 * (pbase + p) + 1];
        float wxv[8], wyv[8], bv[8];
        *(float4*)&wxv[0] = *(const float4*)&W0[o * 8];
        *(float4*)&wxv[4] = *(const float4*)&W0[o * 8 + 4];
        *(float4*)&wyv[0] = *(const float4*)&W0[H + o * 8];
        *(float4*)&wyv[4] = *(const float4*)&W0[H + o * 8 + 4];
        *(float4*)&bv[0]  = *(const float4*)&b0[o * 8];
        *(float4*)&bv[4]  = *(const float4*)&b0[o * 8 + 4];
        float r[6][8];
        #pragma unroll
        for (int u = 0; u < 8; ++u) {
            float a, g1, g2;
            tanh_d2(fmaf(x, wxv[u], fmaf(y, wyv[u], bv[u])), a, g1, g2);
            r[0][u] = a;
            r[1][u] = g1 * wxv[u];
            r[2][u] = g1 * wyv[u];
            r[3][u] = g2 * wxv[u] * wxv[u];
            r[4][u] = g2 * wxv[u] * wyv[u];
            r[5][u] = g2 * wyv[u] * wyv[u];
        }
        #pragma unroll
        for (int pl = 0; pl < 6; ++pl) {
            PK4 q;
            #pragma unroll
            for (int h = 0; h < 4; ++h)
                q.h[h] = __builtin_amdgcn_cvt_pkrtz(r[pl][2*h], r[pl][2*h+1]);
            *(uint4*)&sS[soct(pl, p, o)] = q.u;
        }
    }
    __syncthreads();

    // ---------------- hidden layers ----------------
    for (int layer = 0; layer < 2; ++layer) {
        const _Float16* __restrict__ Wg = Wt + layer * H * H;

        // B-frags (own plane) upfront: 8 x b128, then plane is ours to clobber
        v8h Bf[2][4];
        #pragma unroll
        for (int nt = 0; nt < 2; ++nt)
            #pragma unroll
            for (int kc = 0; kc < 4; ++kc)
                Bf[nt][kc] = *(const v8h*)&sS[soct(wave, nt * 16 + l15, kc * 4 + quad)];

        v4f C[8][2];
        #pragma unroll
        for (int mt = 0; mt < 8; ++mt) { C[mt][0] = (v4f){0,0,0,0}; C[mt][1] = (v4f){0,0,0,0}; }

        #pragma unroll 2
        for (int mt = 0; mt < 8; ++mt) {
            v8h Af[4];
            #pragma unroll
            for (int kc = 0; kc < 4; ++kc)
                Af[kc] = *(const v8h*)&Wg[(mt * 16 + l15) * H + kc * 32 + quad * 8];
            #pragma unroll
            for (int kc = 0; kc < 4; ++kc) {
                C[mt][0] = __builtin_amdgcn_mfma_f32_16x16x32_f16(Af[kc], Bf[0][kc], C[mt][0], 0, 0, 0);
                C[mt][1] = __builtin_amdgcn_mfma_f32_16x16x32_f16(Af[kc], Bf[1][kc], C[mt][1], 0, 0, 0);
            }
        }

        // writeback zT into own plane: lane holds j = mt*16+quad*4+(0..3), p = nt*16+l15
        #pragma unroll
        for (int mt = 0; mt < 8; ++mt)
            #pragma unroll
            for (int nt = 0; nt < 2; ++nt) {
                PK2 q;
                q.h[0] = __builtin_amdgcn_cvt_pkrtz(C[mt][nt][0], C[mt][nt][1]);
                q.h[1] = __builtin_amdgcn_cvt_pkrtz(C[mt][nt][2], C[mt][nt][3]);
                const int p = nt * 16 + l15;
                const int o = mt * 2 + (quad >> 1);
                *(uint2*)&sS[soct(wave, p, o) + (quad & 1) * 4] = q.u;
            }
        __syncthreads();   // all z planes complete

        if (layer == 0) {
            // combine: state1 = tanh chain rule (in-place, task-exclusive)
            for (int i = tid; i < P * 16; i += NT) {
                const int p = i >> 4, o = i & 15;
                const int base = soct(0, p, o);     // plane stride = P*16*8 = 4096
                v8h zp[6];
                #pragma unroll
                for (int pl = 0; pl < 6; ++pl)
                    zp[pl] = *(const v8h*)&sS[base + pl * 4096];
                float bv[8];
                *(float4*)&bv[0] = *(const float4*)&b1[o * 8];
                *(float4*)&bv[4] = *(const float4*)&b1[o * 8 + 4];
                float r[6][8];
                #pragma unroll
                for (int u = 0; u < 8; ++u) {
                    float a, g1, g2;
                    tanh_d2((float)zp[0][u] + bv[u], a, g1, g2);
                    const float tx = (float)zp[1][u], ty = (float)zp[2][u];
                    r[0][u] = a;
                    r[1][u] = g1 * tx;
                    r[2][u] = g1 * ty;
                    r[3][u] = fmaf(g2 * tx, tx, g1 * (float)zp[3][u]);
                    r[4][u] = fmaf(g2 * tx, ty, g1 * (float)zp[4][u]);
                    r[5][u] = fmaf(g2 * ty, ty, g1 * (float)zp[5][u]);
                }
                #pragma unroll
                for (int pl = 0; pl < 6; ++pl) {
                    PK4 q;
                    #pragma unroll
                    for (int h = 0; h < 4; ++h)
                        q.h[h] = __builtin_amdgcn_cvt_pkrtz(r[pl][2*h], r[pl][2*h+1]);
                    *(uint4*)&sS[base + pl * 4096] = q.u;
                }
            }
            __syncthreads();
        } else {
            // final combine fused with W3 dot; 256 threads = (p, octet-pair)
            if (tid < 256) {
                const int p = tid >> 3, oh = tid & 7;
                float oxx = 0.f, oxy = 0.f, oyy = 0.f;
                #pragma unroll
                for (int s = 0; s < 2; ++s) {
                    const int o = oh * 2 + s;
                    const int base = soct(0, p, o);
                    v8h zp[6];
                    #pragma unroll
                    for (int pl = 0; pl < 6; ++pl)
                        zp[pl] = *(const v8h*)&sS[base + pl * 4096];
                    float bv[8], w3v[8];
                    *(float4*)&bv[0]  = *(const float4*)&b2[o * 8];
                    *(float4*)&bv[4]  = *(const float4*)&b2[o * 8 + 4];
                    *(float4*)&w3v[0] = *(const float4*)&W3[o * 8];
                    *(float4*)&w3v[4] = *(const float4*)&W3[o * 8 + 4];
                    #pragma unroll
                    for (int u = 0; u < 8; ++u) {
                        float a, g1, g2;
                        tanh_d2((float)zp[0][u] + bv[u], a, g1, g2);
                        const float tx = (float)zp[1][u], ty = (float)zp[2][u];
                        oxx = fmaf(w3v[u], fmaf(g2 * tx, tx, g1 * (float)zp[3][u]), oxx);
                        oxy = fmaf(w3v[u], fmaf(g2 * tx, ty, g1 * (float)zp[4][u]), oxy);
                        oyy = fmaf(w3v[u], fmaf(g2 * ty, ty, g1 * (float)zp[5][u]), oyy);
                    }
                }
                #pragma unroll
                for (int off = 4; off > 0; off >>= 1) {
                    oxx += __shfl_down(oxx, off, 8);
                    oxy += __shfl_down(oxy, off, 8);
                    oyy += __shfl_down(oyy, off, 8);
                }
                if (oh == 0) {
                    out[pbase + p]         = oxx;
                    out[N + pbase + p]     = oxy;
                    out[2 * N + pbase + p] = oyy;
                }
            }
        }
    }
}

extern "C" void kernel_launch(void* const* d_in, const int* in_sizes, int n_in,
                              void* d_out, int out_size, void* d_ws, size_t ws_size,
                              hipStream_t stream) {
    const float* X  = (const float*)d_in[0];
    const float* W0 = (const float*)d_in[1];
    const float* b0 = (const float*)d_in[2];
    const float* W1 = (const float*)d_in[3];
    const float* b1 = (const float*)d_in[4];
    const float* W2 = (const float*)d_in[5];
    const float* b2 = (const float*)d_in[6];
    const float* W3 = (const float*)d_in[7];
    // d_in[8] = b3: constant offset, zero second derivative -> unused.

    const int N = in_sizes[0] / 2;               // 131072 = 4096 * P
    float* out = (float*)d_out;
    _Float16* ws = (_Float16*)d_ws;              // Wt[2][128][128] f16 = 64 KB

    hipLaunchKernelGGL(wt_convert, dim3(32), dim3(256), 0, stream, W1, W2, ws);

    hipLaunchKernelGGL(pinn_hess_mfma, dim3(N / P), dim3(NT), 0, stream,
                       X, W0, b0, ws, b1, b2, W3, out, N);
}

// Round 7
// 300.968 us; speedup vs baseline: 1.9450x; 1.9450x over previous
//
#include <hip/hip_runtime.h>

#define H   128
#define P   32             // points per block
#define NT  384            // 6 waves: wave w owns state plane w

typedef _Float16 v8h __attribute__((ext_vector_type(8)));
typedef __fp16   h2  __attribute__((ext_vector_type(2)));   // cvt_pkrtz return type
typedef float    v4f __attribute__((ext_vector_type(4)));

union PK4 { h2 h[4]; uint4 u; };       // 8 f16 = 16 B
union PK2 { h2 h[2]; uint2 u; };       // 4 f16 = 8 B

// State plane layout: [pl][p][k], 128 f16 per row, XOR-octet swizzle so both
// row-wise b128 (k-octets at fixed p) and column-wise b64/b128 (p varying)
// accesses are 2-way-bank-aliased (free, m136). Returns f16 index of octet o.
__device__ __forceinline__ int soct(int pl, int p, int o) {
    return ((pl * P + p) * 16 + (o ^ (p & 15))) << 3;
}

// Coalesced tiled transpose+cvt: Wt[layer][j][k] = f16(W[k][j])
__global__ void wt_convert(const float* __restrict__ W1,
                           const float* __restrict__ W2,
                           _Float16* __restrict__ ws) {
    __shared__ float tile[32][33];
    const int b  = blockIdx.x;          // 0..31
    const int l  = b >> 4;
    const int t  = b & 15;
    const int kt = t >> 2, jt = t & 3;
    const float* __restrict__ W = l ? W2 : W1;
    const int tr = threadIdx.x >> 5;    // 0..7
    const int tc = threadIdx.x & 31;
    #pragma unroll
    for (int s = 0; s < 4; ++s)
        tile[tr + s * 8][tc] = W[(kt * 32 + tr + s * 8) * H + jt * 32 + tc];
    __syncthreads();
    #pragma unroll
    for (int s = 0; s < 4; ++s)
        ws[l * H * H + (jt * 32 + tr + s * 8) * H + kt * 32 + tc] =
            (_Float16)tile[tc][tr + s * 8];
}

__device__ __forceinline__ void tanh_d2(float z, float& a, float& g1, float& g2) {
    const float e = __expf(2.f * z);
    a  = 1.f - 2.f / (e + 1.f);
    g1 = 1.f - a * a;
    g2 = -2.f * a * g1;
}

// Second-order forward-mode Hessian via f16 MFMA, zT orientation.
//   GEMM: zT[j][p] = sum_k Wt[j][k] * S[pl][p][k]
//   A = Wt (m=j, global, L1/L2-resident 32KB/layer), B = state (n=p, LDS).
// R6 post-mortem: 64 live accumulators + unroll-2 A-frags blew the 170-reg
// cap of launch_bounds(.,3) -> scratch spill (WRITE_SIZE 1.5 GB). Fix: per-mt
// immediate writeback (8 live acc), explicit 2-deep A prefetch, 128-reg cap.
__global__ __launch_bounds__(NT, 4)
void pinn_hess_mfma(const float* __restrict__ X,
                    const float* __restrict__ W0, const float* __restrict__ b0,
                    const _Float16* __restrict__ Wt,
                    const float* __restrict__ b1, const float* __restrict__ b2,
                    const float* __restrict__ W3,
                    float* __restrict__ out, int N)
{
    __shared__ _Float16 sS[6 * P * H];   // 49152 B, swizzled planes

    const int tid   = threadIdx.x;
    const int wave  = tid >> 6;          // 0..5 == plane id
    const int lane  = tid & 63;
    const int quad  = lane >> 4;
    const int l15   = lane & 15;
    const int pbase = blockIdx.x * P;

    // ---------------- layer 0 (input dim 2, analytic) ----------------
    for (int i = tid; i < P * 16; i += NT) {     // task = (p, j-octet)
        const int p = i >> 4, o = i & 15;
        const float x = X[2 * (pbase + p)];
        const float y = X[2 * (pbase + p) + 1];
        float wxv[8], wyv[8], bv[8];
        *(float4*)&wxv[0] = *(const float4*)&W0[o * 8];
        *(float4*)&wxv[4] = *(const float4*)&W0[o * 8 + 4];
        *(float4*)&wyv[0] = *(const float4*)&W0[H + o * 8];
        *(float4*)&wyv[4] = *(const float4*)&W0[H + o * 8 + 4];
        *(float4*)&bv[0]  = *(const float4*)&b0[o * 8];
        *(float4*)&bv[4]  = *(const float4*)&b0[o * 8 + 4];
        float r[6][8];
        #pragma unroll
        for (int u = 0; u < 8; ++u) {
            float a, g1, g2;
            tanh_d2(fmaf(x, wxv[u], fmaf(y, wyv[u], bv[u])), a, g1, g2);
            r[0][u] = a;
            r[1][u] = g1 * wxv[u];
            r[2][u] = g1 * wyv[u];
            r[3][u] = g2 * wxv[u] * wxv[u];
            r[4][u] = g2 * wxv[u] * wyv[u];
            r[5][u] = g2 * wyv[u] * wyv[u];
        }
        #pragma unroll
        for (int pl = 0; pl < 6; ++pl) {
            PK4 q;
            #pragma unroll
            for (int h = 0; h < 4; ++h)
                q.h[h] = __builtin_amdgcn_cvt_pkrtz(r[pl][2*h], r[pl][2*h+1]);
            *(uint4*)&sS[soct(pl, p, o)] = q.u;
        }
    }
    __syncthreads();

    // ---------------- hidden layers ----------------
    for (int layer = 0; layer < 2; ++layer) {
        const _Float16* __restrict__ Wg = Wt + layer * H * H;

        // B-frags (own plane) upfront: 8 x b128, then plane is ours to clobber
        v8h Bf[2][4];
        #pragma unroll
        for (int nt = 0; nt < 2; ++nt)
            #pragma unroll
            for (int kc = 0; kc < 4; ++kc)
                Bf[nt][kc] = *(const v8h*)&sS[soct(wave, nt * 16 + l15, kc * 4 + quad)];

        auto loadA = [&](v8h* A, int mt) {
            #pragma unroll
            for (int kc = 0; kc < 4; ++kc)
                A[kc] = *(const v8h*)&Wg[(mt * 16 + l15) * H + kc * 32 + quad * 8];
        };
        // writeback zT tile: lane holds j = mt*16+quad*4+(0..3), p = nt*16+l15
        auto wb = [&](const v4f& c, int mt, int nt) {
            PK2 q;
            q.h[0] = __builtin_amdgcn_cvt_pkrtz(c[0], c[1]);
            q.h[1] = __builtin_amdgcn_cvt_pkrtz(c[2], c[3]);
            const int p = nt * 16 + l15;
            const int o = mt * 2 + (quad >> 1);
            *(uint2*)&sS[soct(wave, p, o) + (quad & 1) * 4] = q.u;
        };

        v8h Afa[4], Afb[4];
        loadA(Afa, 0);
        #pragma unroll
        for (int mt = 0; mt < 8; mt += 2) {
            loadA(Afb, mt + 1);
            {
                v4f C0 = (v4f){0,0,0,0}, C1 = (v4f){0,0,0,0};
                #pragma unroll
                for (int kc = 0; kc < 4; ++kc) {
                    C0 = __builtin_amdgcn_mfma_f32_16x16x32_f16(Afa[kc], Bf[0][kc], C0, 0, 0, 0);
                    C1 = __builtin_amdgcn_mfma_f32_16x16x32_f16(Afa[kc], Bf[1][kc], C1, 0, 0, 0);
                }
                wb(C0, mt, 0); wb(C1, mt, 1);
            }
            if (mt + 2 < 8) loadA(Afa, mt + 2);
            {
                v4f C0 = (v4f){0,0,0,0}, C1 = (v4f){0,0,0,0};
                #pragma unroll
                for (int kc = 0; kc < 4; ++kc) {
                    C0 = __builtin_amdgcn_mfma_f32_16x16x32_f16(Afb[kc], Bf[0][kc], C0, 0, 0, 0);
                    C1 = __builtin_amdgcn_mfma_f32_16x16x32_f16(Afb[kc], Bf[1][kc], C1, 0, 0, 0);
                }
                wb(C0, mt + 1, 0); wb(C1, mt + 1, 1);
            }
        }
        __syncthreads();   // all z planes complete

        if (layer == 0) {
            // combine: state1 = tanh chain rule (in-place, task-exclusive)
            for (int i = tid; i < P * 16; i += NT) {
                const int p = i >> 4, o = i & 15;
                const int base = soct(0, p, o);     // plane stride = P*16*8 = 4096
                v8h zp[6];
                #pragma unroll
                for (int pl = 0; pl < 6; ++pl)
                    zp[pl] = *(const v8h*)&sS[base + pl * 4096];
                float bv[8];
                *(float4*)&bv[0] = *(const float4*)&b1[o * 8];
                *(float4*)&bv[4] = *(const float4*)&b1[o * 8 + 4];
                float r[6][8];
                #pragma unroll
                for (int u = 0; u < 8; ++u) {
                    float a, g1, g2;
                    tanh_d2((float)zp[0][u] + bv[u], a, g1, g2);
                    const float tx = (float)zp[1][u], ty = (float)zp[2][u];
                    r[0][u] = a;
                    r[1][u] = g1 * tx;
                    r[2][u] = g1 * ty;
                    r[3][u] = fmaf(g2 * tx, tx, g1 * (float)zp[3][u]);
                    r[4][u] = fmaf(g2 * tx, ty, g1 * (float)zp[4][u]);
                    r[5][u] = fmaf(g2 * ty, ty, g1 * (float)zp[5][u]);
                }
                #pragma unroll
                for (int pl = 0; pl < 6; ++pl) {
                    PK4 q;
                    #pragma unroll
                    for (int h = 0; h < 4; ++h)
                        q.h[h] = __builtin_amdgcn_cvt_pkrtz(r[pl][2*h], r[pl][2*h+1]);
                    *(uint4*)&sS[base + pl * 4096] = q.u;
                }
            }
            __syncthreads();
        } else {
            // final combine fused with W3 dot; 256 threads = (p, octet-pair)
            if (tid < 256) {
                const int p = tid >> 3, oh = tid & 7;
                float oxx = 0.f, oxy = 0.f, oyy = 0.f;
                #pragma unroll
                for (int s = 0; s < 2; ++s) {
                    const int o = oh * 2 + s;
                    const int base = soct(0, p, o);
                    v8h zp[6];
                    #pragma unroll
                    for (int pl = 0; pl < 6; ++pl)
                        zp[pl] = *(const v8h*)&sS[base + pl * 4096];
                    float bv[8], w3v[8];
                    *(float4*)&bv[0]  = *(const float4*)&b2[o * 8];
                    *(float4*)&bv[4]  = *(const float4*)&b2[o * 8 + 4];
                    *(float4*)&w3v[0] = *(const float4*)&W3[o * 8];
                    *(float4*)&w3v[4] = *(const float4*)&W3[o * 8 + 4];
                    #pragma unroll
                    for (int u = 0; u < 8; ++u) {
                        float a, g1, g2;
                        tanh_d2((float)zp[0][u] + bv[u], a, g1, g2);
                        const float tx = (float)zp[1][u], ty = (float)zp[2][u];
                        oxx = fmaf(w3v[u], fmaf(g2 * tx, tx, g1 * (float)zp[3][u]), oxx);
                        oxy = fmaf(w3v[u], fmaf(g2 * tx, ty, g1 * (float)zp[4][u]), oxy);
                        oyy = fmaf(w3v[u], fmaf(g2 * ty, ty, g1 * (float)zp[5][u]), oyy);
                    }
                }
                #pragma unroll
                for (int off = 4; off > 0; off >>= 1) {
                    oxx += __shfl_down(oxx, off, 8);
                    oxy += __shfl_down(oxy, off, 8);
                    oyy += __shfl_down(oyy, off, 8);
                }
                if (oh == 0) {
                    out[pbase + p]         = oxx;
                    out[N + pbase + p]     = oxy;
                    out[2 * N + pbase + p] = oyy;
                }
            }
        }
    }
}

extern "C" void kernel_launch(void* const* d_in, const int* in_sizes, int n_in,
                              void* d_out, int out_size, void* d_ws, size_t ws_size,
                              hipStream_t stream) {
    const float* X  = (const float*)d_in[0];
    const float* W0 = (const float*)d_in[1];
    const float* b0 = (const float*)d_in[2];
    const float* W1 = (const float*)d_in[3];
    const float* b1 = (const float*)d_in[4];
    const float* W2 = (const float*)d_in[5];
    const float* b2 = (const float*)d_in[6];
    const float* W3 = (const float*)d_in[7];
    // d_in[8] = b3: constant offset, zero second derivative -> unused.

    const int N = in_sizes[0] / 2;               // 131072 = 4096 * P
    float* out = (float*)d_out;
    _Float16* ws = (_Float16*)d_ws;              // Wt[2][128][128] f16 = 64 KB

    hipLaunchKernelGGL(wt_convert, dim3(32), dim3(256), 0, stream, W1, W2, ws);

    hipLaunchKernelGGL(pinn_hess_mfma, dim3(N / P), dim3(NT), 0, stream,
                       X, W0, b0, ws, b1, b2, W3, out, N);
}

// Round 8
// 219.047 us; speedup vs baseline: 2.6725x; 1.3740x over previous
//
#include <hip/hip_runtime.h>

#define H    128
#define P    32            // points per block
#define NT   384           // 6 waves: wave w owns state plane w
#define WSTR 40            // staged-W row stride in halves (32 k + 8 pad; 80 B, 16B-aligned, 2-way banks)

typedef _Float16 v8h __attribute__((ext_vector_type(8)));
typedef __fp16   h2  __attribute__((ext_vector_type(2)));   // cvt_pkrtz return type
typedef float    v4f __attribute__((ext_vector_type(4)));

union PK4 { h2 h[4]; uint4 u; };       // 8 f16 = 16 B
union PK2 { h2 h[2]; uint2 u; };       // 4 f16 = 8 B

// State plane layout: [pl][p][k], 128 f16 per row, XOR-octet swizzle: row-wise
// b128 and strided b64 accesses both land 2-way-per-bank (free, m136).
__device__ __forceinline__ int soct(int pl, int p, int o) {
    return ((pl * P + p) * 16 + (o ^ (p & 15))) << 3;
}

// Coalesced tiled transpose+cvt: Wt[layer][j][k] = f16(W[k][j])
__global__ void wt_convert(const float* __restrict__ W1,
                           const float* __restrict__ W2,
                           _Float16* __restrict__ ws) {
    __shared__ float tile[32][33];
    const int b  = blockIdx.x;          // 0..31
    const int l  = b >> 4;
    const int t  = b & 15;
    const int kt = t >> 2, jt = t & 3;
    const float* __restrict__ W = l ? W2 : W1;
    const int tr = threadIdx.x >> 5;    // 0..7
    const int tc = threadIdx.x & 31;
    #pragma unroll
    for (int s = 0; s < 4; ++s)
        tile[tr + s * 8][tc] = W[(kt * 32 + tr + s * 8) * H + jt * 32 + tc];
    __syncthreads();
    #pragma unroll
    for (int s = 0; s < 4; ++s)
        ws[l * H * H + (jt * 32 + tr + s * 8) * H + kt * 32 + tc] =
            (_Float16)tile[tc][tr + s * 8];
}

__device__ __forceinline__ void tanh_d2(float z, float& a, float& g1, float& g2) {
    const float e = __expf(2.f * z);
    a  = 1.f - 2.f / (e + 1.f);
    g1 = 1.f - a * a;
    g2 = -2.f * a * g1;
}

// Second-order forward-mode Hessian via f16 MFMA, zT orientation.
//   GEMM: zT[j][p] = sum_k Wt[j][k] * S[pl][p][k];  A = Wt (LDS-staged,
//   once per block - R7 streamed it per-wave: 1.57 GB at 6.3 TB/s = the
//   251 us wall), B = state (own plane, LDS).
__global__ __launch_bounds__(NT, 4)
void pinn_hess_mfma(const float* __restrict__ X,
                    const float* __restrict__ W0, const float* __restrict__ b0,
                    const _Float16* __restrict__ Wt,
                    const float* __restrict__ b1, const float* __restrict__ b2,
                    const float* __restrict__ W3,
                    float* __restrict__ out, int N)
{
    __shared__ _Float16 sS[6 * P * H];        // 49152 B, swizzled state planes
    __shared__ _Float16 sW[2][H * WSTR];      // 2 x 10240 B, W-chunk double buffer

    const int tid   = threadIdx.x;
    const int wave  = tid >> 6;               // 0..5 == plane id
    const int lane  = tid & 63;
    const int quad  = lane >> 4;
    const int l15   = lane & 15;
    const int pbase = blockIdx.x * P;

    // ---------------- layer 0 (input dim 2, analytic) ----------------
    for (int i = tid; i < P * 16; i += NT) {  // task = (p, j-octet)
        const int p = i >> 4, o = i & 15;
        const float x = X[2 * (pbase + p)];
        const float y = X[2 * (pbase + p) + 1];
        float wxv[8], wyv[8], bv[8];
        *(float4*)&wxv[0] = *(const float4*)&W0[o * 8];
        *(float4*)&wxv[4] = *(const float4*)&W0[o * 8 + 4];
        *(float4*)&wyv[0] = *(const float4*)&W0[H + o * 8];
        *(float4*)&wyv[4] = *(const float4*)&W0[H + o * 8 + 4];
        *(float4*)&bv[0]  = *(const float4*)&b0[o * 8];
        *(float4*)&bv[4]  = *(const float4*)&b0[o * 8 + 4];
        float r[6][8];
        #pragma unroll
        for (int u = 0; u < 8; ++u) {
            float a, g1, g2;
            tanh_d2(fmaf(x, wxv[u], fmaf(y, wyv[u], bv[u])), a, g1, g2);
            r[0][u] = a;
            r[1][u] = g1 * wxv[u];
            r[2][u] = g1 * wyv[u];
            r[3][u] = g2 * wxv[u] * wxv[u];
            r[4][u] = g2 * wxv[u] * wyv[u];
            r[5][u] = g2 * wyv[u] * wyv[u];
        }
        #pragma unroll
        for (int pl = 0; pl < 6; ++pl) {
            PK4 q;
            #pragma unroll
            for (int h = 0; h < 4; ++h)
                q.h[h] = __builtin_amdgcn_cvt_pkrtz(r[pl][2*h], r[pl][2*h+1]);
            *(uint4*)&sS[soct(pl, p, o)] = q.u;
        }
    }

    // ---------------- hidden layers ----------------
    for (int layer = 0; layer < 2; ++layer) {
        const _Float16* __restrict__ Wg = Wt + layer * H * H;

        // stage one 32-k chunk of Wt into sW[buf]: 512 b128 tasks, coalesced
        auto stage = [&](int kc, int buf) {
            for (int c = tid; c < 512; c += NT) {
                const int j = c >> 2, o = c & 3;
                *(v8h*)&sW[buf][j * WSTR + o * 8] =
                    *(const v8h*)&Wg[j * H + kc * 32 + o * 8];
            }
        };

        stage(0, 0);        // sW idle since previous layer's last barrier
        __syncthreads();    // chunk0 visible; state planes (L0/combine) visible

        v4f C[8][2];
        #pragma unroll
        for (int mt = 0; mt < 8; ++mt) { C[mt][0] = (v4f){0,0,0,0}; C[mt][1] = (v4f){0,0,0,0}; }

        for (int kc = 0; kc < 4; ++kc) {
            const int buf = kc & 1;
            if (kc < 3) stage(kc + 1, buf ^ 1);
            // B-frags for this kc from own plane (stable until wb)
            const v8h B0 = *(const v8h*)&sS[soct(wave, l15,      kc * 4 + quad)];
            const v8h B1 = *(const v8h*)&sS[soct(wave, 16 + l15, kc * 4 + quad)];
            #pragma unroll
            for (int mt = 0; mt < 8; ++mt) {
                const v8h A = *(const v8h*)&sW[buf][(mt * 16 + l15) * WSTR + quad * 8];
                C[mt][0] = __builtin_amdgcn_mfma_f32_16x16x32_f16(A, B0, C[mt][0], 0, 0, 0);
                C[mt][1] = __builtin_amdgcn_mfma_f32_16x16x32_f16(A, B1, C[mt][1], 0, 0, 0);
            }
            if (kc == 3) {
                // writeback zT into own plane: j = mt*16+quad*4+(0..3), p = nt*16+l15
                #pragma unroll
                for (int mt = 0; mt < 8; ++mt)
                    #pragma unroll
                    for (int nt = 0; nt < 2; ++nt) {
                        PK2 q;
                        q.h[0] = __builtin_amdgcn_cvt_pkrtz(C[mt][nt][0], C[mt][nt][1]);
                        q.h[1] = __builtin_amdgcn_cvt_pkrtz(C[mt][nt][2], C[mt][nt][3]);
                        const int p = nt * 16 + l15;
                        const int o = mt * 2 + (quad >> 1);
                        *(uint2*)&sS[soct(wave, p, o) + (quad & 1) * 4] = q.u;
                    }
            }
            __syncthreads();   // chunk reads done; next chunk visible; (kc3) z visible
        }

        if (layer == 0) {
            // combine: state1 = tanh chain rule (in-place, task-exclusive)
            for (int i = tid; i < P * 16; i += NT) {
                const int p = i >> 4, o = i & 15;
                const int base = soct(0, p, o);     // plane stride = P*16*8 = 4096
                v8h zp[6];
                #pragma unroll
                for (int pl = 0; pl < 6; ++pl)
                    zp[pl] = *(const v8h*)&sS[base + pl * 4096];
                float bv[8];
                *(float4*)&bv[0] = *(const float4*)&b1[o * 8];
                *(float4*)&bv[4] = *(const float4*)&b1[o * 8 + 4];
                float r[6][8];
                #pragma unroll
                for (int u = 0; u < 8; ++u) {
                    float a, g1, g2;
                    tanh_d2((float)zp[0][u] + bv[u], a, g1, g2);
                    const float tx = (float)zp[1][u], ty = (float)zp[2][u];
                    r[0][u] = a;
                    r[1][u] = g1 * tx;
                    r[2][u] = g1 * ty;
                    r[3][u] = fmaf(g2 * tx, tx, g1 * (float)zp[3][u]);
                    r[4][u] = fmaf(g2 * tx, ty, g1 * (float)zp[4][u]);
                    r[5][u] = fmaf(g2 * ty, ty, g1 * (float)zp[5][u]);
                }
                #pragma unroll
                for (int pl = 0; pl < 6; ++pl) {
                    PK4 q;
                    #pragma unroll
                    for (int h = 0; h < 4; ++h)
                        q.h[h] = __builtin_amdgcn_cvt_pkrtz(r[pl][2*h], r[pl][2*h+1]);
                    *(uint4*)&sS[base + pl * 4096] = q.u;
                }
            }
            // visibility handled by next layer's post-stage barrier
        } else {
            // final combine fused with W3 dot; 256 threads = (p, octet-pair)
            if (tid < 256) {
                const int p = tid >> 3, oh = tid & 7;
                float oxx = 0.f, oxy = 0.f, oyy = 0.f;
                #pragma unroll
                for (int s = 0; s < 2; ++s) {
                    const int o = oh * 2 + s;
                    const int base = soct(0, p, o);
                    v8h zp[6];
                    #pragma unroll
                    for (int pl = 0; pl < 6; ++pl)
                        zp[pl] = *(const v8h*)&sS[base + pl * 4096];
                    float bv[8], w3v[8];
                    *(float4*)&bv[0]  = *(const float4*)&b2[o * 8];
                    *(float4*)&bv[4]  = *(const float4*)&b2[o * 8 + 4];
                    *(float4*)&w3v[0] = *(const float4*)&W3[o * 8];
                    *(float4*)&w3v[4] = *(const float4*)&W3[o * 8 + 4];
                    #pragma unroll
                    for (int u = 0; u < 8; ++u) {
                        float a, g1, g2;
                        tanh_d2((float)zp[0][u] + bv[u], a, g1, g2);
                        const float tx = (float)zp[1][u], ty = (float)zp[2][u];
                        oxx = fmaf(w3v[u], fmaf(g2 * tx, tx, g1 * (float)zp[3][u]), oxx);
                        oxy = fmaf(w3v[u], fmaf(g2 * tx, ty, g1 * (float)zp[4][u]), oxy);
                        oyy = fmaf(w3v[u], fmaf(g2 * ty, ty, g1 * (float)zp[5][u]), oyy);
                    }
                }
                #pragma unroll
                for (int off = 4; off > 0; off >>= 1) {
                    oxx += __shfl_down(oxx, off, 8);
                    oxy += __shfl_down(oxy, off, 8);
                    oyy += __shfl_down(oyy, off, 8);
                }
                if (oh == 0) {
                    out[pbase + p]         = oxx;
                    out[N + pbase + p]     = oxy;
                    out[2 * N + pbase + p] = oyy;
                }
            }
        }
    }
}

extern "C" void kernel_launch(void* const* d_in, const int* in_sizes, int n_in,
                              void* d_out, int out_size, void* d_ws, size_t ws_size,
                              hipStream_t stream) {
    const float* X  = (const float*)d_in[0];
    const float* W0 = (const float*)d_in[1];
    const float* b0 = (const float*)d_in[2];
    const float* W1 = (const float*)d_in[3];
    const float* b1 = (const float*)d_in[4];
    const float* W2 = (const float*)d_in[5];
    const float* b2 = (const float*)d_in[6];
    const float* W3 = (const float*)d_in[7];
    // d_in[8] = b3: constant offset, zero second derivative -> unused.

    const int N = in_sizes[0] / 2;               // 131072 = 4096 * P
    float* out = (float*)d_out;
    _Float16* ws = (_Float16*)d_ws;              // Wt[2][128][128] f16 = 64 KB

    hipLaunchKernelGGL(wt_convert, dim3(32), dim3(256), 0, stream, W1, W2, ws);

    hipLaunchKernelGGL(pinn_hess_mfma, dim3(N / P), dim3(NT), 0, stream,
                       X, W0, b0, ws, b1, b2, W3, out, N);
}

// Round 9
// 164.593 us; speedup vs baseline: 3.5566x; 1.3308x over previous
//
#include <hip/hip_runtime.h>

#define H    128
#define P    32            // points per block
#define NT   768           // 12 waves: wave = plane*2 + mhalf (2 waves per state plane)
#define WSTR 40            // staged-W row stride in halves (32 k + 8 pad; uniform-bank b128)

typedef _Float16 v8h __attribute__((ext_vector_type(8)));
typedef __fp16   h2  __attribute__((ext_vector_type(2)));   // cvt_pkrtz return type
typedef float    v4f __attribute__((ext_vector_type(4)));

union PK4 { h2 h[4]; uint4 u; };       // 8 f16 = 16 B
union PK2 { h2 h[2]; uint2 u; };       // 4 f16 = 8 B

// State plane layout: [pl][p][k], 128 f16 per row, XOR-octet swizzle: row-wise
// b128 and strided b64 accesses both land 2-way-per-bank (free, m136).
__device__ __forceinline__ int soct(int pl, int p, int o) {
    return ((pl * P + p) * 16 + (o ^ (p & 15))) << 3;
}

// Coalesced tiled transpose+cvt: Wt[layer][j][k] = f16(W[k][j])
__global__ void wt_convert(const float* __restrict__ W1,
                           const float* __restrict__ W2,
                           _Float16* __restrict__ ws) {
    __shared__ float tile[32][33];
    const int b  = blockIdx.x;          // 0..31
    const int l  = b >> 4;
    const int t  = b & 15;
    const int kt = t >> 2, jt = t & 3;
    const float* __restrict__ W = l ? W2 : W1;
    const int tr = threadIdx.x >> 5;    // 0..7
    const int tc = threadIdx.x & 31;
    #pragma unroll
    for (int s = 0; s < 4; ++s)
        tile[tr + s * 8][tc] = W[(kt * 32 + tr + s * 8) * H + jt * 32 + tc];
    __syncthreads();
    #pragma unroll
    for (int s = 0; s < 4; ++s)
        ws[l * H * H + (jt * 32 + tr + s * 8) * H + kt * 32 + tc] =
            (_Float16)tile[tc][tr + s * 8];
}

__device__ __forceinline__ void tanh_d2(float z, float& a, float& g1, float& g2) {
    const float e = __expf(2.f * z);
    a  = 1.f - 2.f / (e + 1.f);
    g1 = 1.f - a * a;
    g2 = -2.f * a * g1;
}

// Second-order forward-mode Hessian via f16 MFMA, zT orientation.
// R8 post-mortem: pipes sum to ~120us but dur=167us at Occupancy 18.8% of a
// 37.5% LDS ceiling -> barrier/latency-bound with 6 waves/block. This round:
// 12 waves (2 per plane, split mt), same LDS -> 24 waves/CU (75% ceiling),
// every phase completes in 1 round, C[4][2]=32 regs under the 85-reg cap.
__global__ __launch_bounds__(NT, 6)
void pinn_hess_mfma(const float* __restrict__ X,
                    const float* __restrict__ W0, const float* __restrict__ b0,
                    const _Float16* __restrict__ Wt,
                    const float* __restrict__ b1, const float* __restrict__ b2,
                    const float* __restrict__ W3,
                    float* __restrict__ out, int N)
{
    __shared__ _Float16 sS[6 * P * H];        // 49152 B, swizzled state planes
    __shared__ _Float16 sW[2][H * WSTR];      // 2 x 10240 B, W-chunk double buffer

    const int tid   = threadIdx.x;
    const int wave  = tid >> 6;               // 0..11
    const int plane = wave >> 1;              // 0..5
    const int mhalf = wave & 1;               // m-tile half: mt in [mhalf*4, mhalf*4+4)
    const int lane  = tid & 63;
    const int quad  = lane >> 4;
    const int l15   = lane & 15;
    const int pbase = blockIdx.x * P;

    // ---------------- layer 0 (input dim 2, analytic) ----------------
    for (int i = tid; i < P * 16; i += NT) {  // task = (p, j-octet); 1 round
        const int p = i >> 4, o = i & 15;
        const float x = X[2 * (pbase + p)];
        const float y = X[2 * (pbase + p) + 1];
        float wxv[8], wyv[8], bv[8];
        *(float4*)&wxv[0] = *(const float4*)&W0[o * 8];
        *(float4*)&wxv[4] = *(const float4*)&W0[o * 8 + 4];
        *(float4*)&wyv[0] = *(const float4*)&W0[H + o * 8];
        *(float4*)&wyv[4] = *(const float4*)&W0[H + o * 8 + 4];
        *(float4*)&bv[0]  = *(const float4*)&b0[o * 8];
        *(float4*)&bv[4]  = *(const float4*)&b0[o * 8 + 4];
        float r[6][8];
        #pragma unroll
        for (int u = 0; u < 8; ++u) {
            float a, g1, g2;
            tanh_d2(fmaf(x, wxv[u], fmaf(y, wyv[u], bv[u])), a, g1, g2);
            r[0][u] = a;
            r[1][u] = g1 * wxv[u];
            r[2][u] = g1 * wyv[u];
            r[3][u] = g2 * wxv[u] * wxv[u];
            r[4][u] = g2 * wxv[u] * wyv[u];
            r[5][u] = g2 * wyv[u] * wyv[u];
        }
        #pragma unroll
        for (int pl = 0; pl < 6; ++pl) {
            PK4 q;
            #pragma unroll
            for (int h = 0; h < 4; ++h)
                q.h[h] = __builtin_amdgcn_cvt_pkrtz(r[pl][2*h], r[pl][2*h+1]);
            *(uint4*)&sS[soct(pl, p, o)] = q.u;
        }
    }

    // ---------------- hidden layers ----------------
    for (int layer = 0; layer < 2; ++layer) {
        const _Float16* __restrict__ Wg = Wt + layer * H * H;

        // stage one 32-k chunk of Wt into sW[buf]: 512 b128 tasks, coalesced
        auto stage = [&](int kc, int buf) {
            for (int c = tid; c < 512; c += NT) {
                const int j = c >> 2, o = c & 3;
                *(v8h*)&sW[buf][j * WSTR + o * 8] =
                    *(const v8h*)&Wg[j * H + kc * 32 + o * 8];
            }
        };

        stage(0, 0);        // sW idle since previous layer's last barrier
        __syncthreads();    // chunk0 visible; state planes (L0/combine) visible

        v4f C[4][2];
        #pragma unroll
        for (int m = 0; m < 4; ++m) { C[m][0] = (v4f){0,0,0,0}; C[m][1] = (v4f){0,0,0,0}; }

        for (int kc = 0; kc < 4; ++kc) {
            const int buf = kc & 1;
            if (kc < 3) stage(kc + 1, buf ^ 1);
            // B-frags for this kc from own plane (stable until wb)
            const v8h B0 = *(const v8h*)&sS[soct(plane, l15,      kc * 4 + quad)];
            const v8h B1 = *(const v8h*)&sS[soct(plane, 16 + l15, kc * 4 + quad)];
            #pragma unroll
            for (int m = 0; m < 4; ++m) {
                const int mt = mhalf * 4 + m;
                const v8h A = *(const v8h*)&sW[buf][(mt * 16 + l15) * WSTR + quad * 8];
                C[m][0] = __builtin_amdgcn_mfma_f32_16x16x32_f16(A, B0, C[m][0], 0, 0, 0);
                C[m][1] = __builtin_amdgcn_mfma_f32_16x16x32_f16(A, B1, C[m][1], 0, 0, 0);
            }
            if (kc == 3) {
                // writeback zT into own plane: j = mt*16+quad*4+(0..3), p = nt*16+l15
                #pragma unroll
                for (int m = 0; m < 4; ++m)
                    #pragma unroll
                    for (int nt = 0; nt < 2; ++nt) {
                        PK2 q;
                        q.h[0] = __builtin_amdgcn_cvt_pkrtz(C[m][nt][0], C[m][nt][1]);
                        q.h[1] = __builtin_amdgcn_cvt_pkrtz(C[m][nt][2], C[m][nt][3]);
                        const int mt = mhalf * 4 + m;
                        const int p = nt * 16 + l15;
                        const int o = mt * 2 + (quad >> 1);
                        *(uint2*)&sS[soct(plane, p, o) + (quad & 1) * 4] = q.u;
                    }
            }
            __syncthreads();   // chunk reads done; next chunk visible; (kc3) z visible
        }

        if (layer == 0) {
            // combine: state1 = tanh chain rule (in-place, task-exclusive); 1 round
            for (int i = tid; i < P * 16; i += NT) {
                const int p = i >> 4, o = i & 15;
                const int base = soct(0, p, o);     // plane stride = P*16*8 = 4096
                v8h zp[6];
                #pragma unroll
                for (int pl = 0; pl < 6; ++pl)
                    zp[pl] = *(const v8h*)&sS[base + pl * 4096];
                float bv[8];
                *(float4*)&bv[0] = *(const float4*)&b1[o * 8];
                *(float4*)&bv[4] = *(const float4*)&b1[o * 8 + 4];
                float r[6][8];
                #pragma unroll
                for (int u = 0; u < 8; ++u) {
                    float a, g1, g2;
                    tanh_d2((float)zp[0][u] + bv[u], a, g1, g2);
                    const float tx = (float)zp[1][u], ty = (float)zp[2][u];
                    r[0][u] = a;
                    r[1][u] = g1 * tx;
                    r[2][u] = g1 * ty;
                    r[3][u] = fmaf(g2 * tx, tx, g1 * (float)zp[3][u]);
                    r[4][u] = fmaf(g2 * tx, ty, g1 * (float)zp[4][u]);
                    r[5][u] = fmaf(g2 * ty, ty, g1 * (float)zp[5][u]);
                }
                #pragma unroll
                for (int pl = 0; pl < 6; ++pl) {
                    PK4 q;
                    #pragma unroll
                    for (int h = 0; h < 4; ++h)
                        q.h[h] = __builtin_amdgcn_cvt_pkrtz(r[pl][2*h], r[pl][2*h+1]);
                    *(uint4*)&sS[base + pl * 4096] = q.u;
                }
            }
            // visibility handled by next layer's post-stage barrier
        } else {
            // final combine fused with W3 dot; 512 threads = (p, octet); 16/point
            if (tid < 512) {
                const int p = tid >> 4, o = tid & 15;
                float oxx = 0.f, oxy = 0.f, oyy = 0.f;
                const int base = soct(0, p, o);
                v8h zp[6];
                #pragma unroll
                for (int pl = 0; pl < 6; ++pl)
                    zp[pl] = *(const v8h*)&sS[base + pl * 4096];
                float bv[8], w3v[8];
                *(float4*)&bv[0]  = *(const float4*)&b2[o * 8];
                *(float4*)&bv[4]  = *(const float4*)&b2[o * 8 + 4];
                *(float4*)&w3v[0] = *(const float4*)&W3[o * 8];
                *(float4*)&w3v[4] = *(const float4*)&W3[o * 8 + 4];
                #pragma unroll
                for (int u = 0; u < 8; ++u) {
                    float a, g1, g2;
                    tanh_d2((float)zp[0][u] + bv[u], a, g1, g2);
                    const float tx = (float)zp[1][u], ty = (float)zp[2][u];
                    oxx = fmaf(w3v[u], fmaf(g2 * tx, tx, g1 * (float)zp[3][u]), oxx);
                    oxy = fmaf(w3v[u], fmaf(g2 * tx, ty, g1 * (float)zp[4][u]), oxy);
                    oyy = fmaf(w3v[u], fmaf(g2 * ty, ty, g1 * (float)zp[5][u]), oyy);
                }
                // 16 lanes per point, contiguous within the wave
                #pragma unroll
                for (int off = 8; off > 0; off >>= 1) {
                    oxx += __shfl_down(oxx, off, 16);
                    oxy += __shfl_down(oxy, off, 16);
                    oyy += __shfl_down(oyy, off, 16);
                }
                if (o == 0) {
                    out[pbase + p]         = oxx;
                    out[N + pbase + p]     = oxy;
                    out[2 * N + pbase + p] = oyy;
                }
            }
        }
    }
}

extern "C" void kernel_launch(void* const* d_in, const int* in_sizes, int n_in,
                              void* d_out, int out_size, void* d_ws, size_t ws_size,
                              hipStream_t stream) {
    const float* X  = (const float*)d_in[0];
    const float* W0 = (const float*)d_in[1];
    const float* b0 = (const float*)d_in[2];
    const float* W1 = (const float*)d_in[3];
    const float* b1 = (const float*)d_in[4];
    const float* W2 = (const float*)d_in[5];
    const float* b2 = (const float*)d_in[6];
    const float* W3 = (const float*)d_in[7];
    // d_in[8] = b3: constant offset, zero second derivative -> unused.

    const int N = in_sizes[0] / 2;               // 131072 = 4096 * P
    float* out = (float*)d_out;
    _Float16* ws = (_Float16*)d_ws;              // Wt[2][128][128] f16 = 64 KB

    hipLaunchKernelGGL(wt_convert, dim3(32), dim3(256), 0, stream, W1, W2, ws);

    hipLaunchKernelGGL(pinn_hess_mfma, dim3(N / P), dim3(NT), 0, stream,
                       X, W0, b0, ws, b1, b2, W3, out, N);
}

// Round 10
// 156.824 us; speedup vs baseline: 3.7328x; 1.0495x over previous
//
#include <hip/hip_runtime.h>

#define H    128
#define P    32            // points per block
#define NT   512           // 8 waves: wave = jpair*2 + phalf
#define WSTR 40            // staged-W row stride in halves (32 k + 8 pad)

typedef _Float16 v8h __attribute__((ext_vector_type(8)));
typedef __fp16   h2  __attribute__((ext_vector_type(2)));   // cvt_pkrtz return type
typedef float    v4f __attribute__((ext_vector_type(4)));

union PK4 { h2 h[4]; uint4 u; };       // 8 f16 = 16 B

// State plane layout: [pl][p][k], 128 f16 per row, XOR-octet swizzle; returns
// f16 index of octet o of row p (row accesses b128-able, scatter ~4-way).
__device__ __forceinline__ int soct(int pl, int p, int o) {
    return ((pl * P + p) * 16 + (o ^ (p & 15))) << 3;
}

// Wide prepass: 256 blocks x 64 threads, one k-pair per thread.
// Wt[l][j][k] = f16(W_l[k][j]). Gather reads (L2), coalesced b32 writes.
__global__ void wt_convert(const float* __restrict__ W1,
                           const float* __restrict__ W2,
                           _Float16* __restrict__ ws) {
    const int t = blockIdx.x * 64 + threadIdx.x;   // 0..16383
    const int l = t >> 13;
    const int r = t & 8191;
    const int j = r >> 6, kp = r & 63;
    const float* __restrict__ W = l ? W2 : W1;
    const float a = W[(2 * kp) * H + j];
    const float b = W[(2 * kp + 1) * H + j];
    union { h2 h; unsigned u; } q;
    q.h = __builtin_amdgcn_cvt_pkrtz(a, b);
    ((unsigned*)ws)[t] = q.u;                      // halves 2t,2t+1 = Wt[l][j][2kp..]
}

__device__ __forceinline__ void tanh_d2(float z, float& a, float& g1, float& g2) {
    const float e = __expf(2.f * z);
    a  = 1.f - 2.f / (e + 1.f);
    g1 = 1.f - a * a;
    g2 = -2.f * a * g1;
}

// Second-order forward-mode Hessian via f16 MFMA, z orientation (A = state,
// B = Wt). Wave (phalf,jpair) computes C[6 planes][2 j-tiles] -> all 6 planes
// of z(p,j) land in ONE lane in f32 -> tanh chain rule entirely in registers
// (R9's z writeback + re-read + 48 cvts/task eliminated).
// C layout (m89/m91): col j = l15, row p = quad*4+reg.
__global__ __launch_bounds__(NT, 4)
void pinn_hess_mfma(const float* __restrict__ X,
                    const float* __restrict__ W0, const float* __restrict__ b0,
                    const _Float16* __restrict__ Wt,
                    const float* __restrict__ b1, const float* __restrict__ b2,
                    const float* __restrict__ W3,
                    float* __restrict__ out, int N)
{
    __shared__ _Float16 sS[6 * P * H];        // 49152 B, swizzled state planes
    __shared__ _Float16 sW[2][H * WSTR];      // 2 x 10240 B, W-chunk double buffer

    const int tid   = threadIdx.x;
    const int wave  = tid >> 6;               // 0..7
    const int phalf = wave & 1;               // p-half: rows phalf*16..+16
    const int jpair = wave >> 1;              // j-tile pair: cols jpair*32..+32
    const int lane  = tid & 63;
    const int quad  = lane >> 4;
    const int l15   = lane & 15;
    const int pbase = blockIdx.x * P;

    // ---------------- layer 0 (input dim 2, analytic); 512 tasks = 1/thread --
    {
        const int p = tid >> 4, o = tid & 15;
        const float x = X[2 * (pbase + p)];
        const float y = X[2 * (pbase + p) + 1];
        float wxv[8], wyv[8], bv[8];
        *(float4*)&wxv[0] = *(const float4*)&W0[o * 8];
        *(float4*)&wxv[4] = *(const float4*)&W0[o * 8 + 4];
        *(float4*)&wyv[0] = *(const float4*)&W0[H + o * 8];
        *(float4*)&wyv[4] = *(const float4*)&W0[H + o * 8 + 4];
        *(float4*)&bv[0]  = *(const float4*)&b0[o * 8];
        *(float4*)&bv[4]  = *(const float4*)&b0[o * 8 + 4];
        float r[6][8];
        #pragma unroll
        for (int u = 0; u < 8; ++u) {
            float a, g1, g2;
            tanh_d2(fmaf(x, wxv[u], fmaf(y, wyv[u], bv[u])), a, g1, g2);
            r[0][u] = a;
            r[1][u] = g1 * wxv[u];
            r[2][u] = g1 * wyv[u];
            r[3][u] = g2 * wxv[u] * wxv[u];
            r[4][u] = g2 * wxv[u] * wyv[u];
            r[5][u] = g2 * wyv[u] * wyv[u];
        }
        #pragma unroll
        for (int pl = 0; pl < 6; ++pl) {
            PK4 q;
            #pragma unroll
            for (int h = 0; h < 4; ++h)
                q.h[h] = __builtin_amdgcn_cvt_pkrtz(r[pl][2*h], r[pl][2*h+1]);
            *(uint4*)&sS[soct(pl, p, o)] = q.u;
        }
    }

    // ---------------- hidden layers ----------------
    for (int layer = 0; layer < 2; ++layer) {
        const _Float16* __restrict__ Wg = Wt + layer * H * H;

        // stage one 32-k chunk of Wt: 512 b128 tasks = 1/thread, coalesced
        auto stage = [&](int kc, int buf) {
            const int j = tid >> 2, o = tid & 3;
            *(v8h*)&sW[buf][j * WSTR + o * 8] =
                *(const v8h*)&Wg[j * H + kc * 32 + o * 8];
        };

        stage(0, 0);        // sW[0] free since prev layer's kc2 barrier
        __syncthreads();    // chunk0 + state writes (L0 / prev combine) visible

        v4f C[6][2];
        #pragma unroll
        for (int pl = 0; pl < 6; ++pl) { C[pl][0] = (v4f){0,0,0,0}; C[pl][1] = (v4f){0,0,0,0}; }

        for (int kc = 0; kc < 4; ++kc) {
            const int buf = kc & 1;
            if (kc < 3) stage(kc + 1, buf ^ 1);
            // B-frags: rows j = jpair*32 + nt*16 + l15, k-octet quad of chunk
            const v8h B0 = *(const v8h*)&sW[buf][(jpair * 32 + l15)      * WSTR + quad * 8];
            const v8h B1 = *(const v8h*)&sW[buf][(jpair * 32 + 16 + l15) * WSTR + quad * 8];
            #pragma unroll
            for (int pl = 0; pl < 6; ++pl) {
                // A-frag: state plane pl, row p = phalf*16 + l15, octet kc*4+quad
                const v8h A = *(const v8h*)&sS[soct(pl, phalf * 16 + l15, kc * 4 + quad)];
                C[pl][0] = __builtin_amdgcn_mfma_f32_16x16x32_f16(A, B0, C[pl][0], 0, 0, 0);
                C[pl][1] = __builtin_amdgcn_mfma_f32_16x16x32_f16(A, B1, C[pl][1], 0, 0, 0);
            }
            __syncthreads();   // kc<3: dbuf swap; kc==3: drain reads before scatter
        }

        if (layer == 0) {
            // in-register tanh chain rule; scatter new state (b16, ~4-way banks)
            #pragma unroll
            for (int nt = 0; nt < 2; ++nt) {
                const int j  = jpair * 32 + nt * 16 + l15;
                const int ob = j >> 3, wi = j & 7;
                const float bb = b1[j];
                #pragma unroll
                for (int r = 0; r < 4; ++r) {
                    const int p = phalf * 16 + quad * 4 + r;
                    float a, g1, g2;
                    tanh_d2(C[0][nt][r] + bb, a, g1, g2);
                    const float tx = C[1][nt][r], ty = C[2][nt][r];
                    sS[soct(0, p, ob) + wi] = (_Float16)a;
                    sS[soct(1, p, ob) + wi] = (_Float16)(g1 * tx);
                    sS[soct(2, p, ob) + wi] = (_Float16)(g1 * ty);
                    sS[soct(3, p, ob) + wi] = (_Float16)fmaf(g2 * tx, tx, g1 * C[3][nt][r]);
                    sS[soct(4, p, ob) + wi] = (_Float16)fmaf(g2 * tx, ty, g1 * C[4][nt][r]);
                    sS[soct(5, p, ob) + wi] = (_Float16)fmaf(g2 * ty, ty, g1 * C[5][nt][r]);
                }
            }
            // visibility: next layer's post-stage(0,0) barrier
        } else {
            // final combine + W3 dot in registers; reduce j over l15 then jpair
            float hxx[4] = {0,0,0,0}, hxy[4] = {0,0,0,0}, hyy[4] = {0,0,0,0};
            #pragma unroll
            for (int nt = 0; nt < 2; ++nt) {
                const int j = jpair * 32 + nt * 16 + l15;
                const float bb = b2[j];
                const float w3 = W3[j];
                #pragma unroll
                for (int r = 0; r < 4; ++r) {
                    float a, g1, g2;
                    tanh_d2(C[0][nt][r] + bb, a, g1, g2);
                    const float tx = C[1][nt][r], ty = C[2][nt][r];
                    hxx[r] = fmaf(w3, fmaf(g2 * tx, tx, g1 * C[3][nt][r]), hxx[r]);
                    hxy[r] = fmaf(w3, fmaf(g2 * tx, ty, g1 * C[4][nt][r]), hxy[r]);
                    hyy[r] = fmaf(w3, fmaf(g2 * ty, ty, g1 * C[5][nt][r]), hyy[r]);
                }
            }
            #pragma unroll
            for (int off = 8; off > 0; off >>= 1)
                #pragma unroll
                for (int r = 0; r < 4; ++r) {
                    hxx[r] += __shfl_down(hxx[r], off, 16);
                    hxy[r] += __shfl_down(hxy[r], off, 16);
                    hyy[r] += __shfl_down(hyy[r], off, 16);
                }
            // sW[0] free (last read at kc2); scratch partial[c][jpair][p]
            float* sRed = (float*)&sW[0][0];
            if (l15 == 0) {
                #pragma unroll
                for (int r = 0; r < 4; ++r) {
                    const int p = phalf * 16 + quad * 4 + r;
                    sRed[0 * 128 + jpair * 32 + p] = hxx[r];
                    sRed[1 * 128 + jpair * 32 + p] = hxy[r];
                    sRed[2 * 128 + jpair * 32 + p] = hyy[r];
                }
            }
            __syncthreads();
            if (tid < 96) {
                const int c = tid >> 5, p = tid & 31;
                float acc = 0.f;
                #pragma unroll
                for (int jp = 0; jp < 4; ++jp)
                    acc += sRed[c * 128 + jp * 32 + p];
                out[c * N + pbase + p] = acc;
            }
        }
    }
}

extern "C" void kernel_launch(void* const* d_in, const int* in_sizes, int n_in,
                              void* d_out, int out_size, void* d_ws, size_t ws_size,
                              hipStream_t stream) {
    const float* X  = (const float*)d_in[0];
    const float* W0 = (const float*)d_in[1];
    const float* b0 = (const float*)d_in[2];
    const float* W1 = (const float*)d_in[3];
    const float* b1 = (const float*)d_in[4];
    const float* W2 = (const float*)d_in[5];
    const float* b2 = (const float*)d_in[6];
    const float* W3 = (const float*)d_in[7];
    // d_in[8] = b3: constant offset, zero second derivative -> unused.

    const int N = in_sizes[0] / 2;               // 131072 = 4096 * P
    float* out = (float*)d_out;
    _Float16* ws = (_Float16*)d_ws;              // Wt[2][128][128] f16 = 64 KB

    hipLaunchKernelGGL(wt_convert, dim3(256), dim3(64), 0, stream, W1, W2, ws);

    hipLaunchKernelGGL(pinn_hess_mfma, dim3(N / P), dim3(NT), 0, stream,
                       X, W0, b0, ws, b1, b2, W3, out, N);
}